// Round 4
// baseline (211.171 us; speedup 1.0000x reference)
//
#include <hip/hip_runtime.h>
#include <hip/hip_bf16.h>
#include <float.h>

// Problem constants (fixed by setup_inputs): B=4, N=M=4096, D=3.
#define BATCH 4
#define NPTS  4096
#define TOT   (BATCH * NPTS)   // 16384

// ---------------------------------------------------------------------------
// Kernel 1: pack points into float4 {x, y, z, |p|^2}.
// rr computed as x*x + y*y + z*z left-to-right, matching jnp.sum(x*x, -1).
// ---------------------------------------------------------------------------
__global__ __launch_bounds__(256) void pack_kernel(
    const float* __restrict__ gts, const float* __restrict__ preds,
    float4* __restrict__ pkG, float4* __restrict__ pkP)
{
    int i = blockIdx.x * blockDim.x + threadIdx.x;   // 0 .. 2*TOT-1
    if (i >= 2 * TOT) return;
    const float* src = (i < TOT) ? gts : preds;
    float4* dst      = (i < TOT) ? pkG : pkP;
    int k            = (i < TOT) ? i : i - TOT;
    float x = src[3 * k + 0];
    float y = src[3 * k + 1];
    float z = src[3 * k + 2];
    float rr = __fadd_rn(__fadd_rn(__fmul_rn(x, x), __fmul_rn(y, y)), __fmul_rn(z, z));
    dst[k] = make_float4(x, y, z, rr);
}

// ---------------------------------------------------------------------------
// Kernel 2 (templated on R = number of completed mask rounds):
// For each "own" point, find min + argmin over all "other" points, skipping
// entries masked in rounds t < R. Handles both directions in one launch:
//   blocks [0, half)      -> row direction  (own = gts,  other = preds)
//   blocks [half, grid)   -> col direction  (own = preds, other = gts)
// Exclusion rule for own-index i vs candidate j (row dir shown; col is the
// mirror): masked iff j == i_s2f_t[b,i]  OR  i_f2s_t[b,j] == i.
// One wave processes ROWS=4 consecutive own indices (amortizes candidate
// loads 4x). Strict '<' with ascending j keeps the first (lowest-index)
// minimum per lane; the butterfly reduce is lexicographic on (val, idx),
// matching numpy argmin tie-breaking.
// ---------------------------------------------------------------------------
template<int R>
__global__ __launch_bounds__(256) void round_kernel(
    const float4* __restrict__ pkG, const float4* __restrict__ pkP,
    const int* __restrict__ is0, const int* __restrict__ is1, const int* __restrict__ is2,
    const int* __restrict__ if0, const int* __restrict__ if1, const int* __restrict__ if2,
    float* __restrict__ dS, int* __restrict__ iS,
    float* __restrict__ dF, int* __restrict__ iF,
    int do_rows)
{
    int half    = do_rows ? (gridDim.x >> 1) : gridDim.x;
    bool isRow  = do_rows && ((int)blockIdx.x < half);
    int dirBlk  = isRow ? blockIdx.x : (blockIdx.x - (do_rows ? half : 0));

    const float4* own = isRow ? pkG : pkP;
    const float4* oth = isRow ? pkP : pkG;
    const int* exOwn0 = isRow ? is0 : if0;
    const int* exOwn1 = isRow ? is1 : if1;
    const int* exOwn2 = isRow ? is2 : if2;
    const int* exOth0 = isRow ? if0 : is0;
    const int* exOth1 = isRow ? if1 : is1;
    const int* exOth2 = isRow ? if2 : is2;
    float* dOut = isRow ? dS : dF;
    int*   iOut = isRow ? iS : iF;

    int lane = threadIdx.x & 63;
    int wave = threadIdx.x >> 6;
    int ownBase = dirBlk * 16 + wave * 4;        // 4 waves/block * 4 rows/wave
    int b = ownBase >> 12;                       // / 4096 (16 | 4096 -> no straddle)
    int obase = b << 12;

    float ox[4], oy[4], oz[4], orr[4];
    int ownIn[4];
    int oe0[4], oe1[4], oe2[4];
    #pragma unroll
    for (int r = 0; r < 4; ++r) {
        float4 p = own[ownBase + r];
        ox[r] = p.x; oy[r] = p.y; oz[r] = p.z; orr[r] = p.w;
        ownIn[r] = (ownBase & (NPTS - 1)) + r;
        oe0[r] = 0; oe1[r] = 0; oe2[r] = 0;
        if (R > 0) oe0[r] = exOwn0[ownBase + r];
        if (R > 1) oe1[r] = exOwn1[ownBase + r];
        if (R > 2) oe2[r] = exOwn2[ownBase + r];
    }

    float best[4]; int bidx[4];
    #pragma unroll
    for (int r = 0; r < 4; ++r) { best[r] = FLT_MAX; bidx[r] = 0; }

    for (int j = lane; j < NPTS; j += 64) {
        float4 q = oth[obase + j];
        int eo0 = 0, eo1 = 0, eo2 = 0;
        if (R > 0) eo0 = exOth0[obase + j];
        if (R > 1) eo1 = exOth1[obase + j];
        if (R > 2) eo2 = exOth2[obase + j];
        #pragma unroll
        for (int r = 0; r < 4; ++r) {
            // zz = x0*y0 + x1*y1 + x2*y2, left-to-right, no contraction
            float zz = __fadd_rn(__fadd_rn(__fmul_rn(ox[r], q.x),
                                           __fmul_rn(oy[r], q.y)),
                                 __fmul_rn(oz[r], q.z));
            // (rx+ry) - 2*zz : 2*zz is exact, so fma(-2,zz,s) == s - 2*zz
            float d = __fmaf_rn(-2.0f, zz, __fadd_rn(orr[r], q.w));
            bool ex = false;
            if (R > 0) ex = ex || (j == oe0[r]) || (eo0 == ownIn[r]);
            if (R > 1) ex = ex || (j == oe1[r]) || (eo1 == ownIn[r]);
            if (R > 2) ex = ex || (j == oe2[r]) || (eo2 == ownIn[r]);
            if (ex) d = FLT_MAX;
            if (d < best[r]) { best[r] = d; bidx[r] = j; }
        }
    }

    #pragma unroll
    for (int r = 0; r < 4; ++r) {
        float v = best[r]; int ix = bidx[r];
        #pragma unroll
        for (int off = 32; off > 0; off >>= 1) {
            float v2 = __shfl_xor(v, off);
            int   i2 = __shfl_xor(ix, off);
            if (v2 < v || (v2 == v && i2 < ix)) { v = v2; ix = i2; }
        }
        if (lane == 0) {
            iOut[ownBase + r] = ix;
            if (dOut) dOut[ownBase + r] = v;
        }
    }
}

// ---------------------------------------------------------------------------
// Kernel 3: per-(batch, segment) partial sums.
// 16 blocks: b = blk>>2, seg = blk&3 (1024 m's each). Computes:
//   champ partial = sum d_f2s0 + d_s2f0 over the slice
//   s_k partial   = sum_m dot(preds[b,i0] - preds[b,ik], normals[b,m]), k=1..3
// Deterministic tree reduction (no atomics).
// ---------------------------------------------------------------------------
__global__ __launch_bounds__(256) void normal_kernel(
    const float* __restrict__ preds, const float* __restrict__ normals,
    const float* __restrict__ dS, const float* __restrict__ dF,
    const int* __restrict__ if0, const int* __restrict__ if1,
    const int* __restrict__ if2, const int* __restrict__ if3,
    float4* __restrict__ partials)
{
    int b   = blockIdx.x >> 2;
    int seg = blockIdx.x & 3;
    int t   = threadIdx.x;

    const float* pp = preds + (size_t)b * NPTS * 3;
    float champ = 0.f, s1 = 0.f, s2 = 0.f, s3 = 0.f;

    for (int it = 0; it < 4; ++it) {
        int m  = seg * 1024 + it * 256 + t;
        int gi = b * NPTS + m;
        champ += dF[gi] + dS[gi];

        int i0 = if0[gi];
        float p0x = pp[3 * i0 + 0], p0y = pp[3 * i0 + 1], p0z = pp[3 * i0 + 2];
        float nx = normals[3 * gi + 0], ny = normals[3 * gi + 1], nz = normals[3 * gi + 2];

        int iA = if1[gi];
        s1 += (p0x - pp[3 * iA + 0]) * nx + (p0y - pp[3 * iA + 1]) * ny + (p0z - pp[3 * iA + 2]) * nz;
        int iB = if2[gi];
        s2 += (p0x - pp[3 * iB + 0]) * nx + (p0y - pp[3 * iB + 1]) * ny + (p0z - pp[3 * iB + 2]) * nz;
        int iC = if3[gi];
        s3 += (p0x - pp[3 * iC + 0]) * nx + (p0y - pp[3 * iC + 1]) * ny + (p0z - pp[3 * iC + 2]) * nz;
    }

    // wave butterfly, then cross-wave via LDS
    #pragma unroll
    for (int off = 32; off > 0; off >>= 1) {
        champ += __shfl_xor(champ, off);
        s1    += __shfl_xor(s1, off);
        s2    += __shfl_xor(s2, off);
        s3    += __shfl_xor(s3, off);
    }
    __shared__ float4 red[4];
    int wave = t >> 6, lane = t & 63;
    if (lane == 0) red[wave] = make_float4(champ, s1, s2, s3);
    __syncthreads();
    if (t == 0) {
        float4 a = red[0];
        for (int w = 1; w < 4; ++w) {
            a.x += red[w].x; a.y += red[w].y; a.z += red[w].z; a.w += red[w].w;
        }
        partials[blockIdx.x] = a;
    }
}

// ---------------------------------------------------------------------------
// Kernel 4: combine 16 partials -> scalar.
// result = 1 + champfer + 10 * sum_k sum_b |s[b][k]|   (k outer, matching ref)
// ---------------------------------------------------------------------------
__global__ void final_kernel(const float4* __restrict__ partials, float* __restrict__ out)
{
    if (blockIdx.x == 0 && threadIdx.x == 0) {
        float champ = 0.f;
        float s[BATCH][3];
        for (int b = 0; b < BATCH; ++b) for (int k = 0; k < 3; ++k) s[b][k] = 0.f;
        for (int blk = 0; blk < 16; ++blk) {
            float4 p = partials[blk];
            int b = blk >> 2;
            champ   += p.x;
            s[b][0] += p.y;
            s[b][1] += p.z;
            s[b][2] += p.w;
        }
        float nl = 0.f;
        for (int k = 0; k < 3; ++k)
            for (int b = 0; b < BATCH; ++b)
                nl += fabsf(s[b][k]);
        out[0] = 1.0f + champ + 10.0f * nl;
    }
}

// ---------------------------------------------------------------------------
// Launch. Workspace layout (~1.2 MB):
//   pkG float4[16384] | pkP float4[16384] | iS0..iS2 int[16384] each |
//   iF0..iF3 int[16384] each | dS0 float[16384] | dF0 float[16384] |
//   partials float4[16]
// ---------------------------------------------------------------------------
extern "C" void kernel_launch(void* const* d_in, const int* in_sizes, int n_in,
                              void* d_out, int out_size, void* d_ws, size_t ws_size,
                              hipStream_t stream) {
    const float* gts     = (const float*)d_in[0];
    const float* preds   = (const float*)d_in[1];
    const float* normals = (const float*)d_in[2];
    float* out = (float*)d_out;

    char* ws = (char*)d_ws;
    float4* pkG = (float4*)ws;
    float4* pkP = (float4*)(ws + 262144);
    int* iS0 = (int*)(ws + 524288);
    int* iS1 = iS0 + TOT;
    int* iS2 = iS1 + TOT;
    int* iF0 = iS2 + TOT;
    int* iF1 = iF0 + TOT;
    int* iF2 = iF1 + TOT;
    int* iF3 = iF2 + TOT;
    float* dS0 = (float*)(iF3 + TOT);
    float* dF0 = dS0 + TOT;
    float4* partials = (float4*)(dF0 + TOT);

    pack_kernel<<<(2 * TOT + 255) / 256, 256, 0, stream>>>(gts, preds, pkG, pkP);

    // Round 0: both directions, no exclusions.
    round_kernel<0><<<2048, 256, 0, stream>>>(pkG, pkP,
        nullptr, nullptr, nullptr, nullptr, nullptr, nullptr,
        dS0, iS0, dF0, iF0, 1);

    // Round 1: exclude round-0 masks.
    round_kernel<1><<<2048, 256, 0, stream>>>(pkG, pkP,
        iS0, nullptr, nullptr, iF0, nullptr, nullptr,
        nullptr, iS1, nullptr, iF1, 1);

    // Round 2: exclude rounds 0-1.
    round_kernel<2><<<2048, 256, 0, stream>>>(pkG, pkP,
        iS0, iS1, nullptr, iF0, iF1, nullptr,
        nullptr, iS2, nullptr, iF2, 1);

    // Round 3: col direction only (only i_f2s_3 is consumed), exclude rounds 0-2.
    round_kernel<3><<<1024, 256, 0, stream>>>(pkG, pkP,
        iS0, iS1, iS2, iF0, iF1, iF2,
        nullptr, nullptr, nullptr, iF3, 0);

    normal_kernel<<<16, 256, 0, stream>>>(preds, normals, dS0, dF0,
                                          iF0, iF1, iF2, iF3, partials);
    final_kernel<<<1, 64, 0, stream>>>(partials, out);
}